// Round 11
// baseline (357.620 us; speedup 1.0000x reference)
//
#include <hip/hip_runtime.h>
#include <cstdint>

// NewsEncoder: B=8192, L=64, D=256, H=8, DH=32, VOCAB=50000.
// R11: replace both tail SGEMMs with prep_P + one MFMA GEMM:
//   P_h = WV[:,h32]@WO[h32,:]  (precomputed, bf16, stored transposed Pt[n][k])
//   out[8192,256] = cbf[8192,2048](bf16 y) @ P  -- 8.6 GFLOP MFMA (~5-10us)
// main/xbar/cgemm/ebf unchanged from R10 (main is VALU+latency pinned; next
// round target). Workspace: mbf | xbf | tkn | cbf | ebf | ptb  => ~62.4 MB

using f32x4  = __attribute__((ext_vector_type(4))) float;
using bf16x8 = __attribute__((ext_vector_type(8))) short;

__device__ __forceinline__ unsigned int pack2bf(float a, float b) {
  unsigned int ua = __builtin_bit_cast(unsigned int, a);
  unsigned int ub = __builtin_bit_cast(unsigned int, b);
  ua = (ua + 0x7fffu + ((ua >> 16) & 1u)) >> 16;   // RTNE to bf16
  ub = (ub + 0x7fffu + ((ub >> 16) & 1u)) >> 16;
  return ua | (ub << 16);
}
__device__ __forceinline__ unsigned short bf1(float a) {
  unsigned int ua = __builtin_bit_cast(unsigned int, a);
  ua = (ua + 0x7fffu + ((ua >> 16) & 1u)) >> 16;
  return (unsigned short)ua;
}
__device__ __forceinline__ float ubf(unsigned int u) {
  return __builtin_bit_cast(float, u << 16);
}

// ---- prep: WOd[d] = WO[d,:]@dw;  m[h][d] = sum_j WV[d][h*32+j]*WOd[h*32+j] (bf16 out)
__global__ __launch_bounds__(256) void prep_kernel(const float* __restrict__ WV,
                                                   const float* __restrict__ WO,
                                                   const float* __restrict__ dw,
                                                   unsigned short* __restrict__ mbf) {
  __shared__ float wod[256];
  const int t = threadIdx.x;
  float acc = 0.f;
  for (int e = 0; e < 256; e += 4) {
    const float4 w4 = *(const float4*)(WO + (size_t)t * 256 + e);
    const float4 d4 = *(const float4*)(dw + e);
    acc += w4.x * d4.x + w4.y * d4.y + w4.z * d4.z + w4.w * d4.w;
  }
  wod[t] = acc;
  __syncthreads();
  for (int h = 0; h < 8; ++h) {
    float a = 0.f;
    for (int j = 0; j < 32; j += 4) {
      const float4 w4 = *(const float4*)(WV + (size_t)t * 256 + h * 32 + j);
      a += w4.x * wod[h*32+j] + w4.y * wod[h*32+j+1] + w4.z * wod[h*32+j+2] + w4.w * wod[h*32+j+3];
    }
    const float o = __shfl_xor(a, 1);
    if (!(t & 1)) ((unsigned int*)mbf)[h * 128 + (t >> 1)] = pack2bf(a, o);
  }
}

// ---- prep_T: Tkn[n=h*256+e][d] = sum_j WQ[d][hj]*WK[e][hj] + WK[d][hj]*WQ[e][hj] (bf16)
__global__ __launch_bounds__(256) void prep_T(const float* __restrict__ WQ,
                                              const float* __restrict__ WK,
                                              unsigned short* __restrict__ tkn) {
  __shared__ float ek[8][32], eq[8][32];
  const int t = threadIdx.x;
  const int n0 = blockIdx.x * 8;          // 8 n-rows per block, same head
  const int h  = n0 >> 8;
  {
    const int ei = t >> 5, j = t & 31;
    const int e = (n0 & 255) + ei;
    ek[ei][j] = WK[(size_t)e * 256 + h * 32 + j];
    eq[ei][j] = WQ[(size_t)e * 256 + h * 32 + j];
  }
  __syncthreads();
  float wqd[32], wkd[32];
#pragma unroll
  for (int j = 0; j < 32; j += 4) {
    *(float4*)(wqd + j) = *(const float4*)(WQ + (size_t)t * 256 + h * 32 + j);
    *(float4*)(wkd + j) = *(const float4*)(WK + (size_t)t * 256 + h * 32 + j);
  }
#pragma unroll
  for (int ei = 0; ei < 8; ++ei) {
    float a = 0.f;
#pragma unroll
    for (int j = 0; j < 32; ++j) a += wqd[j] * ek[ei][j] + wkd[j] * eq[ei][j];
    const float o = __shfl_xor(a, 1);
    if (!(t & 1)) ((unsigned int*)tkn)[(size_t)(n0 + ei) * 128 + (t >> 1)] = pack2bf(a, o);
  }
}

// ---- prep_P: Pt[n][h*256+d] = sum_j WV[d][h*32+j] * WO[h*32+j][n]  (bf16, transposed)
__global__ __launch_bounds__(256) void prep_P(const float* __restrict__ WV,
                                              const float* __restrict__ WO,
                                              unsigned short* __restrict__ ptb) {
  __shared__ float wvs[32][32];    // WV[d0+dd][h32+j]
  __shared__ float wos[32][256];   // WO[h32+j][n]
  const int t = threadIdx.x;
  const int h = blockIdx.x, d0 = blockIdx.y * 32;
  {
    const int dd = t >> 3, jq = (t & 7) * 4;
    *(float4*)(&wvs[dd][jq]) = *(const float4*)(WV + (size_t)(d0 + dd) * 256 + h * 32 + jq);
    const int c4 = (t & 63) * 4;
#pragma unroll
    for (int jj = 0; jj < 8; ++jj) {
      const int j = (t >> 6) * 8 + jj;
      *(float4*)(&wos[j][c4]) = *(const float4*)(WO + (size_t)(h * 32 + j) * 256 + c4);
    }
  }
  __syncthreads();
  const int n = t;
#pragma unroll 4
  for (int dd = 0; dd < 32; ++dd) {
    float a = 0.f;
#pragma unroll
    for (int j = 0; j < 32; ++j) a += wvs[dd][j] * wos[j][n];
    ptb[(size_t)n * 2048 + h * 256 + d0 + dd] = bf1(a);
  }
}

// ---- K0: convert emb (f32) -> ebf (bf16)
__global__ __launch_bounds__(256) void ebf_kernel(const float4* __restrict__ emb4,
                                                  uint2* __restrict__ out2, int n) {
  for (int i = blockIdx.x * 256 + threadIdx.x; i < n; i += gridDim.x * 256) {
    const float4 v = emb4[i];
    uint2 pk;
    pk.x = pack2bf(v.x, v.y);
    pk.y = pack2bf(v.z, v.w);
    out2[i] = pk;
  }
}

// ---- K1: xbar[b][d] = mean_l ebf[tok[b][l]][d]  (bf16 in/out, f32 accum)
__global__ __launch_bounds__(256) void xbar_kernel(const int* __restrict__ tokens,
                                                   const unsigned short* __restrict__ ebf,
                                                   unsigned short* __restrict__ xbf) {
  __shared__ int tok[64];
  __shared__ float part[4][64][4];          // 4 KB
  const int b = blockIdx.x, t = threadIdx.x;
  if (t < 64) tok[t] = tokens[b * 64 + t];
  __syncthreads();
  const int cp = t & 63, rg = t >> 6;       // col-quad, row-group
  const uint2* e2 = (const uint2*)ebf;
  float s0 = 0.f, s1 = 0.f, s2 = 0.f, s3 = 0.f;
#pragma unroll
  for (int ri = 0; ri < 16; ++ri) {
    const uint2 u = e2[(size_t)tok[rg * 16 + ri] * 64 + cp];
    s0 += ubf(u.x & 0xffffu); s1 += ubf(u.x >> 16);
    s2 += ubf(u.y & 0xffffu); s3 += ubf(u.y >> 16);
  }
  *(float4*)part[rg][cp] = make_float4(s0, s1, s2, s3);
  __syncthreads();
  if (t < 64) {
    const float4 p0 = *(const float4*)part[0][t];
    const float4 p1 = *(const float4*)part[1][t];
    const float4 p2 = *(const float4*)part[2][t];
    const float4 p3 = *(const float4*)part[3][t];
    const float a0 = (p0.x + p1.x + p2.x + p3.x) * (1.f / 64.f);
    const float a1 = (p0.y + p1.y + p2.y + p3.y) * (1.f / 64.f);
    const float a2 = (p0.z + p1.z + p2.z + p3.z) * (1.f / 64.f);
    const float a3 = (p0.w + p1.w + p2.w + p3.w) * (1.f / 64.f);
    uint2 pk;
    pk.x = pack2bf(a0, a1);
    pk.y = pack2bf(a2, a3);
    *(uint2*)((unsigned int*)xbf + (size_t)b * 128 + 2 * t) = pk;
  }
}

// ---- K2: cbf[b][n] = sum_d xbf[b][d] * tkn[n][d]  (bf16 MFMA GEMM)
__global__ __launch_bounds__(256) void cgemm(const unsigned short* __restrict__ xbf,
                                             const unsigned short* __restrict__ tkn,
                                             unsigned short* __restrict__ cbf) {
  __shared__ unsigned short As[64 * 264];   // 33,792 B
  const int t = threadIdx.x;
  const int m0 = blockIdx.x * 64, n0 = blockIdx.y * 64;
#pragma unroll
  for (int it = 0; it < 8; ++it) {
    const int idx = it * 256 + t;
    const int row = idx >> 5, c = idx & 31;
    const uint4 v = *(const uint4*)(xbf + (size_t)(m0 + row) * 256 + c * 8);
    *(uint4*)(As + row * 264 + c * 8) = v;
  }
  __syncthreads();
  const int wv = t >> 6, l = t & 63;
  const int g = l >> 4, r = l & 15;
#pragma unroll
  for (int nt = 0; nt < 4; ++nt) {
    const int n = n0 + nt * 16 + r;
    f32x4 acc = {0.f, 0.f, 0.f, 0.f};
#pragma unroll
    for (int kk = 0; kk < 8; ++kk) {
      const bf16x8 a  = *(const bf16x8*)(As + (16 * wv + r) * 264 + kk * 32 + g * 8);
      const bf16x8 bb = *(const bf16x8*)(tkn + (size_t)n * 256 + kk * 32 + g * 8);
      acc = __builtin_amdgcn_mfma_f32_16x16x32_bf16(a, bb, acc, 0, 0, 0);
    }
#pragma unroll
    for (int i = 0; i < 4; ++i)
      cbf[(size_t)(m0 + 16 * wv + g * 4 + i) * 2048 + n] = bf1(acc[i]);
  }
}

// ---- K3: main v3 — x staged once in LDS; 3 barriers; all-wave phases;
//          per-head y phase reads x from LDS. (unchanged from R10)
__global__ __launch_bounds__(256) void main_kernel(const int* __restrict__ tokens,
                                                   const unsigned short* __restrict__ ebf,
                                                   const unsigned short* __restrict__ mbf,
                                                   const float* __restrict__ dense_b,
                                                   unsigned short* __restrict__ cbf) {
  __shared__ unsigned short xl[64 * 264];   // 33,792 B: x bf16, row stride 264
  __shared__ float wslds[64 * 17];          // 4,352 B: cols 0-7 w->p, 8-15 s
  const int t = threadIdx.x;
  const int b = blockIdx.x;
  const int wv = t >> 6, l = t & 63;
  const int g = l >> 4, r = l & 15;
  // Stage x: tokens read per-thread (32-thread broadcast), 8 indep uint4 loads
  {
    const uint4* eb4 = (const uint4*)ebf;   // 16 B = 8 bf16; 32 uint4 per row
#pragma unroll
    for (int it = 0; it < 8; ++it) {
      const int idx = it * 256 + t;          // 0..2047
      const int row = idx >> 5, c = idx & 31;
      const int tk = tokens[b * 64 + row];
      *(uint4*)(xl + row * 264 + c * 8) = eb4[(size_t)tk * 32 + c];
    }
  }
  __syncthreads();                          // barrier 1: x staged
  // Phase 1: [W|S] = X[64,256] @ [c|m]^T; A from LDS, B from global (L2-hot)
  {
    const unsigned short* arow = xl + (16 * wv + r) * 264;
    const unsigned short* brow = (r < 8) ? (cbf + (size_t)b * 2048 + r * 256)
                                         : (mbf + (size_t)(r - 8) * 256);
    f32x4 acc = {0.f, 0.f, 0.f, 0.f};
#pragma unroll
    for (int kk = 0; kk < 8; ++kk) {
      const bf16x8 a  = *(const bf16x8*)(arow + kk * 32 + g * 8);
      const bf16x8 bb = *(const bf16x8*)(brow + kk * 32 + g * 8);
      acc = __builtin_amdgcn_mfma_f32_16x16x32_bf16(a, bb, acc, 0, 0, 0);
    }
#pragma unroll
    for (int i = 0; i < 4; ++i)
      wslds[(16 * wv + g * 4 + i) * 17 + r] = acc[i];
  }
  __syncthreads();                          // barrier 2: logits complete
  // Phase 2: per-head softmax over seq (wave w handles heads 2w, 2w+1)
  {
#pragma unroll
    for (int hh = 0; hh < 2; ++hh) {
      const int h = 2 * wv + hh;
      const float v = wslds[l * 17 + h];
      float mx = v;
#pragma unroll
      for (int sft = 32; sft; sft >>= 1) mx = fmaxf(mx, __shfl_xor(mx, sft));
      const float e = expf(v - mx);
      float sm = e;
#pragma unroll
      for (int sft = 32; sft; sft >>= 1) sm += __shfl_xor(sm, sft);
      wslds[l * 17 + h] = e / sm;
    }
  }
  __syncthreads();                          // barrier 3: p complete
  // Phase 3 (every wave, redundant): scores softmax -> coef in registers
  float cc0, cc1;
  {
    float p[8], sv[8];
#pragma unroll
    for (int h = 0; h < 8; ++h) { p[h] = wslds[l*17 + h]; sv[h] = wslds[l*17 + 8 + h]; }
    float sc = dense_b[0];
#pragma unroll
    for (int h = 0; h < 8; ++h) sc += p[h] * sv[h];
    float mx = sc;
#pragma unroll
    for (int sft = 32; sft; sft >>= 1) mx = fmaxf(mx, __shfl_xor(mx, sft));
    const float e = expf(sc - mx);
    float sm = e;
#pragma unroll
    for (int sft = 32; sft; sft >>= 1) sm += __shfl_xor(sm, sft);
    const float attn = e / sm;
    float co[8];
#pragma unroll
    for (int h = 0; h < 8; ++h) co[h] = attn * p[h];
    if      (wv == 0) { cc0 = co[0]; cc1 = co[1]; }
    else if (wv == 1) { cc0 = co[2]; cc1 = co[3]; }
    else if (wv == 2) { cc0 = co[4]; cc1 = co[5]; }
    else              { cc0 = co[6]; cc1 = co[7]; }
  }
  // Phase 4: y by head — wave w owns h=2w,2w+1; lane owns 4 d-cols; x from LDS
  {
    const unsigned int* xu = (const unsigned int*)xl;
    float y0[4] = {}, y1[4] = {};
#pragma unroll
    for (int ll = 0; ll < 64; ++ll) {
      const uint2 xv = *(const uint2*)(xu + ll * 132 + l * 2);
      const float c0 = __shfl(cc0, ll);
      const float c1 = __shfl(cc1, ll);
      const float x0 = ubf(xv.x & 0xffffu);
      const float x1 = ubf(xv.x >> 16);
      const float x2 = ubf(xv.y & 0xffffu);
      const float x3 = ubf(xv.y >> 16);
      y0[0] += c0 * x0; y0[1] += c0 * x1; y0[2] += c0 * x2; y0[3] += c0 * x3;
      y1[0] += c1 * x0; y1[1] += c1 * x1; y1[2] += c1 * x2; y1[3] += c1 * x3;
    }
    uint2 pk0, pk1;
    pk0.x = pack2bf(y0[0], y0[1]); pk0.y = pack2bf(y0[2], y0[3]);
    pk1.x = pack2bf(y1[0], y1[1]); pk1.y = pack2bf(y1[2], y1[3]);
    *(uint2*)(cbf + (size_t)b * 2048 + (2 * wv) * 256 + l * 4)     = pk0;
    *(uint2*)(cbf + (size_t)b * 2048 + (2 * wv + 1) * 256 + l * 4) = pk1;
  }
}

// ---- K4: out[8192,256] = cbf[8192,2048] @ P  (MFMA; B read via Pt[n][k])
__global__ __launch_bounds__(256) void pgemm(const unsigned short* __restrict__ cbf,
                                             const unsigned short* __restrict__ ptb,
                                             float* __restrict__ out) {
  __shared__ unsigned short As[32 * 264];   // 16,896 B: 32 rows x 256 bf16 chunk
  const int t = threadIdx.x;
  const int m0 = blockIdx.x * 32;
  const int wv = t >> 6, l = t & 63;
  const int g = l >> 4, r = l & 15;
  const int mt = wv & 1;                    // m-tile (2 x 16 rows)
  const int ng0 = (wv >> 1) * 8;            // 8 n-tiles per wave
  f32x4 acc[8] = {};
  for (int kc = 0; kc < 8; ++kc) {          // K chunks of 256
#pragma unroll
    for (int it = 0; it < 4; ++it) {
      const int idx = it * 256 + t;          // 0..1023
      const int row = idx >> 5, c = idx & 31;
      const uint4 v = *(const uint4*)(cbf + (size_t)(m0 + row) * 2048 + kc * 256 + c * 8);
      *(uint4*)(As + row * 264 + c * 8) = v;
    }
    __syncthreads();
#pragma unroll
    for (int kk = 0; kk < 8; ++kk) {
      const bf16x8 a = *(const bf16x8*)(As + (16 * mt + r) * 264 + kk * 32 + g * 8);
#pragma unroll
      for (int nt = 0; nt < 8; ++nt) {
        const int n = (ng0 + nt) * 16 + r;
        const bf16x8 bb = *(const bf16x8*)(ptb + (size_t)n * 2048 + kc * 256 + kk * 32 + g * 8);
        acc[nt] = __builtin_amdgcn_mfma_f32_16x16x32_bf16(a, bb, acc[nt], 0, 0, 0);
      }
    }
    __syncthreads();
  }
#pragma unroll
  for (int nt = 0; nt < 8; ++nt) {
    const int n = (ng0 + nt) * 16 + r;
#pragma unroll
    for (int i = 0; i < 4; ++i)
      out[(size_t)(m0 + 16 * mt + g * 4 + i) * 256 + n] = acc[nt][i];
  }
}

extern "C" void kernel_launch(void* const* d_in, const int* in_sizes, int n_in,
                              void* d_out, int out_size, void* d_ws, size_t ws_size,
                              hipStream_t stream) {
  const int*   tokens = (const int*)d_in[0];
  const float* emb    = (const float*)d_in[1];
  const float* WQ     = (const float*)d_in[2];
  const float* WK     = (const float*)d_in[3];
  const float* WV     = (const float*)d_in[4];
  const float* WO     = (const float*)d_in[5];
  const float* dw     = (const float*)d_in[6];
  const float* db     = (const float*)d_in[7];
  float* out = (float*)d_out;

  // ushort-unit layout
  unsigned short* base = (unsigned short*)d_ws;
  unsigned short* mbf  = base;                           // 2048
  unsigned short* xbf  = base + 2048;                    // 8192*256   (4 MB)
  unsigned short* tkn  = xbf + (size_t)8192 * 256;       // 2048*256   (1 MB)
  unsigned short* cbf  = tkn + (size_t)2048 * 256;       // 8192*2048  (32 MB)
  unsigned short* ebf  = cbf + (size_t)8192 * 2048;      // 50000*256  (25.6 MB)
  unsigned short* ptb  = ebf + (size_t)50000 * 256;      // 256*2048   (1 MB)

  const size_t need_bytes = (size_t)(2048 + 8192*256 + 2048*256 + 8192*2048
                                     + 50000*256 + 256*2048) * 2;
  if (ws_size < need_bytes) return;  // deterministic no-op guard

  prep_kernel<<<dim3(1), dim3(256), 0, stream>>>(WV, WO, dw, mbf);
  prep_T<<<dim3(256), dim3(256), 0, stream>>>(WQ, WK, tkn);
  prep_P<<<dim3(8, 8), dim3(256), 0, stream>>>(WV, WO, ptb);
  // emb f32 -> ebf bf16 (50000*256)
  ebf_kernel<<<dim3(2048), dim3(256), 0, stream>>>((const float4*)emb, (uint2*)ebf,
                                                   50000 * 64);
  xbar_kernel<<<dim3(8192), dim3(256), 0, stream>>>(tokens, ebf, xbf);
  // c[b][n] for all b,n in one MFMA GEMM
  cgemm<<<dim3(128, 32), dim3(256), 0, stream>>>(xbf, tkn, cbf);
  // main per-sample: logits, softmaxes, y (overwrites c, bf16)
  main_kernel<<<dim3(8192), dim3(256), 0, stream>>>(tokens, ebf, mbf, db, cbf);
  // out = Y @ P in one MFMA GEMM (replaces both tail SGEMMs)
  pgemm<<<dim3(256), dim3(256), 0, stream>>>(cbf, ptb, out);
}

// Round 12
// 299.032 us; speedup vs baseline: 1.1959x; 1.1959x over previous
//
#include <hip/hip_runtime.h>
#include <cstdint>

// NewsEncoder: B=8192, L=64, D=256, H=8, DH=32, VOCAB=50000.
// R12: pgemm v2 — R11's pgemm was latency-dead at 1 wave/SIMD (256 blocks,
// occ 11%, MfmaUtil 2.6%). Re-shaped to cgemm's proven geometry: grid (128,4),
// 64x64 tile, K=2048 in 8 staged chunks of 256. Everything else unchanged.
// Workspace: mbf | xbf | tkn | cbf | ebf | ptb  => ~62.4 MB

using f32x4  = __attribute__((ext_vector_type(4))) float;
using bf16x8 = __attribute__((ext_vector_type(8))) short;

__device__ __forceinline__ unsigned int pack2bf(float a, float b) {
  unsigned int ua = __builtin_bit_cast(unsigned int, a);
  unsigned int ub = __builtin_bit_cast(unsigned int, b);
  ua = (ua + 0x7fffu + ((ua >> 16) & 1u)) >> 16;   // RTNE to bf16
  ub = (ub + 0x7fffu + ((ub >> 16) & 1u)) >> 16;
  return ua | (ub << 16);
}
__device__ __forceinline__ unsigned short bf1(float a) {
  unsigned int ua = __builtin_bit_cast(unsigned int, a);
  ua = (ua + 0x7fffu + ((ua >> 16) & 1u)) >> 16;
  return (unsigned short)ua;
}
__device__ __forceinline__ float ubf(unsigned int u) {
  return __builtin_bit_cast(float, u << 16);
}

// ---- prep: WOd[d] = WO[d,:]@dw;  m[h][d] = sum_j WV[d][h*32+j]*WOd[h*32+j] (bf16 out)
__global__ __launch_bounds__(256) void prep_kernel(const float* __restrict__ WV,
                                                   const float* __restrict__ WO,
                                                   const float* __restrict__ dw,
                                                   unsigned short* __restrict__ mbf) {
  __shared__ float wod[256];
  const int t = threadIdx.x;
  float acc = 0.f;
  for (int e = 0; e < 256; e += 4) {
    const float4 w4 = *(const float4*)(WO + (size_t)t * 256 + e);
    const float4 d4 = *(const float4*)(dw + e);
    acc += w4.x * d4.x + w4.y * d4.y + w4.z * d4.z + w4.w * d4.w;
  }
  wod[t] = acc;
  __syncthreads();
  for (int h = 0; h < 8; ++h) {
    float a = 0.f;
    for (int j = 0; j < 32; j += 4) {
      const float4 w4 = *(const float4*)(WV + (size_t)t * 256 + h * 32 + j);
      a += w4.x * wod[h*32+j] + w4.y * wod[h*32+j+1] + w4.z * wod[h*32+j+2] + w4.w * wod[h*32+j+3];
    }
    const float o = __shfl_xor(a, 1);
    if (!(t & 1)) ((unsigned int*)mbf)[h * 128 + (t >> 1)] = pack2bf(a, o);
  }
}

// ---- prep_T: Tkn[n=h*256+e][d] = sum_j WQ[d][hj]*WK[e][hj] + WK[d][hj]*WQ[e][hj] (bf16)
__global__ __launch_bounds__(256) void prep_T(const float* __restrict__ WQ,
                                              const float* __restrict__ WK,
                                              unsigned short* __restrict__ tkn) {
  __shared__ float ek[8][32], eq[8][32];
  const int t = threadIdx.x;
  const int n0 = blockIdx.x * 8;          // 8 n-rows per block, same head
  const int h  = n0 >> 8;
  {
    const int ei = t >> 5, j = t & 31;
    const int e = (n0 & 255) + ei;
    ek[ei][j] = WK[(size_t)e * 256 + h * 32 + j];
    eq[ei][j] = WQ[(size_t)e * 256 + h * 32 + j];
  }
  __syncthreads();
  float wqd[32], wkd[32];
#pragma unroll
  for (int j = 0; j < 32; j += 4) {
    *(float4*)(wqd + j) = *(const float4*)(WQ + (size_t)t * 256 + h * 32 + j);
    *(float4*)(wkd + j) = *(const float4*)(WK + (size_t)t * 256 + h * 32 + j);
  }
#pragma unroll
  for (int ei = 0; ei < 8; ++ei) {
    float a = 0.f;
#pragma unroll
    for (int j = 0; j < 32; ++j) a += wqd[j] * ek[ei][j] + wkd[j] * eq[ei][j];
    const float o = __shfl_xor(a, 1);
    if (!(t & 1)) ((unsigned int*)tkn)[(size_t)(n0 + ei) * 128 + (t >> 1)] = pack2bf(a, o);
  }
}

// ---- prep_P: Pt[n][h*256+d] = sum_j WV[d][h*32+j] * WO[h*32+j][n]  (bf16, transposed)
__global__ __launch_bounds__(256) void prep_P(const float* __restrict__ WV,
                                              const float* __restrict__ WO,
                                              unsigned short* __restrict__ ptb) {
  __shared__ float wvs[32][32];    // WV[d0+dd][h32+j]
  __shared__ float wos[32][256];   // WO[h32+j][n]
  const int t = threadIdx.x;
  const int h = blockIdx.x, d0 = blockIdx.y * 32;
  {
    const int dd = t >> 3, jq = (t & 7) * 4;
    *(float4*)(&wvs[dd][jq]) = *(const float4*)(WV + (size_t)(d0 + dd) * 256 + h * 32 + jq);
    const int c4 = (t & 63) * 4;
#pragma unroll
    for (int jj = 0; jj < 8; ++jj) {
      const int j = (t >> 6) * 8 + jj;
      *(float4*)(&wos[j][c4]) = *(const float4*)(WO + (size_t)(h * 32 + j) * 256 + c4);
    }
  }
  __syncthreads();
  const int n = t;
#pragma unroll 4
  for (int dd = 0; dd < 32; ++dd) {
    float a = 0.f;
#pragma unroll
    for (int j = 0; j < 32; ++j) a += wvs[dd][j] * wos[j][n];
    ptb[(size_t)n * 2048 + h * 256 + d0 + dd] = bf1(a);
  }
}

// ---- K0: convert emb (f32) -> ebf (bf16)
__global__ __launch_bounds__(256) void ebf_kernel(const float4* __restrict__ emb4,
                                                  uint2* __restrict__ out2, int n) {
  for (int i = blockIdx.x * 256 + threadIdx.x; i < n; i += gridDim.x * 256) {
    const float4 v = emb4[i];
    uint2 pk;
    pk.x = pack2bf(v.x, v.y);
    pk.y = pack2bf(v.z, v.w);
    out2[i] = pk;
  }
}

// ---- K1: xbar[b][d] = mean_l ebf[tok[b][l]][d]  (bf16 in/out, f32 accum)
__global__ __launch_bounds__(256) void xbar_kernel(const int* __restrict__ tokens,
                                                   const unsigned short* __restrict__ ebf,
                                                   unsigned short* __restrict__ xbf) {
  __shared__ int tok[64];
  __shared__ float part[4][64][4];          // 4 KB
  const int b = blockIdx.x, t = threadIdx.x;
  if (t < 64) tok[t] = tokens[b * 64 + t];
  __syncthreads();
  const int cp = t & 63, rg = t >> 6;       // col-quad, row-group
  const uint2* e2 = (const uint2*)ebf;
  float s0 = 0.f, s1 = 0.f, s2 = 0.f, s3 = 0.f;
#pragma unroll
  for (int ri = 0; ri < 16; ++ri) {
    const uint2 u = e2[(size_t)tok[rg * 16 + ri] * 64 + cp];
    s0 += ubf(u.x & 0xffffu); s1 += ubf(u.x >> 16);
    s2 += ubf(u.y & 0xffffu); s3 += ubf(u.y >> 16);
  }
  *(float4*)part[rg][cp] = make_float4(s0, s1, s2, s3);
  __syncthreads();
  if (t < 64) {
    const float4 p0 = *(const float4*)part[0][t];
    const float4 p1 = *(const float4*)part[1][t];
    const float4 p2 = *(const float4*)part[2][t];
    const float4 p3 = *(const float4*)part[3][t];
    const float a0 = (p0.x + p1.x + p2.x + p3.x) * (1.f / 64.f);
    const float a1 = (p0.y + p1.y + p2.y + p3.y) * (1.f / 64.f);
    const float a2 = (p0.z + p1.z + p2.z + p3.z) * (1.f / 64.f);
    const float a3 = (p0.w + p1.w + p2.w + p3.w) * (1.f / 64.f);
    uint2 pk;
    pk.x = pack2bf(a0, a1);
    pk.y = pack2bf(a2, a3);
    *(uint2*)((unsigned int*)xbf + (size_t)b * 128 + 2 * t) = pk;
  }
}

// ---- K2: cbf[b][n] = sum_d xbf[b][d] * tkn[n][d]  (bf16 MFMA GEMM)
__global__ __launch_bounds__(256) void cgemm(const unsigned short* __restrict__ xbf,
                                             const unsigned short* __restrict__ tkn,
                                             unsigned short* __restrict__ cbf) {
  __shared__ unsigned short As[64 * 264];   // 33,792 B
  const int t = threadIdx.x;
  const int m0 = blockIdx.x * 64, n0 = blockIdx.y * 64;
#pragma unroll
  for (int it = 0; it < 8; ++it) {
    const int idx = it * 256 + t;
    const int row = idx >> 5, c = idx & 31;
    const uint4 v = *(const uint4*)(xbf + (size_t)(m0 + row) * 256 + c * 8);
    *(uint4*)(As + row * 264 + c * 8) = v;
  }
  __syncthreads();
  const int wv = t >> 6, l = t & 63;
  const int g = l >> 4, r = l & 15;
#pragma unroll
  for (int nt = 0; nt < 4; ++nt) {
    const int n = n0 + nt * 16 + r;
    f32x4 acc = {0.f, 0.f, 0.f, 0.f};
#pragma unroll
    for (int kk = 0; kk < 8; ++kk) {
      const bf16x8 a  = *(const bf16x8*)(As + (16 * wv + r) * 264 + kk * 32 + g * 8);
      const bf16x8 bb = *(const bf16x8*)(tkn + (size_t)n * 256 + kk * 32 + g * 8);
      acc = __builtin_amdgcn_mfma_f32_16x16x32_bf16(a, bb, acc, 0, 0, 0);
    }
#pragma unroll
    for (int i = 0; i < 4; ++i)
      cbf[(size_t)(m0 + 16 * wv + g * 4 + i) * 2048 + n] = bf1(acc[i]);
  }
}

// ---- K3: main v3 — x staged once in LDS; 3 barriers; all-wave phases;
//          per-head y phase reads x from LDS. (unchanged from R10)
__global__ __launch_bounds__(256) void main_kernel(const int* __restrict__ tokens,
                                                   const unsigned short* __restrict__ ebf,
                                                   const unsigned short* __restrict__ mbf,
                                                   const float* __restrict__ dense_b,
                                                   unsigned short* __restrict__ cbf) {
  __shared__ unsigned short xl[64 * 264];   // 33,792 B: x bf16, row stride 264
  __shared__ float wslds[64 * 17];          // 4,352 B: cols 0-7 w->p, 8-15 s
  const int t = threadIdx.x;
  const int b = blockIdx.x;
  const int wv = t >> 6, l = t & 63;
  const int g = l >> 4, r = l & 15;
  // Stage x: tokens read per-thread (32-thread broadcast), 8 indep uint4 loads
  {
    const uint4* eb4 = (const uint4*)ebf;   // 16 B = 8 bf16; 32 uint4 per row
#pragma unroll
    for (int it = 0; it < 8; ++it) {
      const int idx = it * 256 + t;          // 0..2047
      const int row = idx >> 5, c = idx & 31;
      const int tk = tokens[b * 64 + row];
      *(uint4*)(xl + row * 264 + c * 8) = eb4[(size_t)tk * 32 + c];
    }
  }
  __syncthreads();                          // barrier 1: x staged
  // Phase 1: [W|S] = X[64,256] @ [c|m]^T; A from LDS, B from global (L2-hot)
  {
    const unsigned short* arow = xl + (16 * wv + r) * 264;
    const unsigned short* brow = (r < 8) ? (cbf + (size_t)b * 2048 + r * 256)
                                         : (mbf + (size_t)(r - 8) * 256);
    f32x4 acc = {0.f, 0.f, 0.f, 0.f};
#pragma unroll
    for (int kk = 0; kk < 8; ++kk) {
      const bf16x8 a  = *(const bf16x8*)(arow + kk * 32 + g * 8);
      const bf16x8 bb = *(const bf16x8*)(brow + kk * 32 + g * 8);
      acc = __builtin_amdgcn_mfma_f32_16x16x32_bf16(a, bb, acc, 0, 0, 0);
    }
#pragma unroll
    for (int i = 0; i < 4; ++i)
      wslds[(16 * wv + g * 4 + i) * 17 + r] = acc[i];
  }
  __syncthreads();                          // barrier 2: logits complete
  // Phase 2: per-head softmax over seq (wave w handles heads 2w, 2w+1)
  {
#pragma unroll
    for (int hh = 0; hh < 2; ++hh) {
      const int h = 2 * wv + hh;
      const float v = wslds[l * 17 + h];
      float mx = v;
#pragma unroll
      for (int sft = 32; sft; sft >>= 1) mx = fmaxf(mx, __shfl_xor(mx, sft));
      const float e = expf(v - mx);
      float sm = e;
#pragma unroll
      for (int sft = 32; sft; sft >>= 1) sm += __shfl_xor(sm, sft);
      wslds[l * 17 + h] = e / sm;
    }
  }
  __syncthreads();                          // barrier 3: p complete
  // Phase 3 (every wave, redundant): scores softmax -> coef in registers
  float cc0, cc1;
  {
    float p[8], sv[8];
#pragma unroll
    for (int h = 0; h < 8; ++h) { p[h] = wslds[l*17 + h]; sv[h] = wslds[l*17 + 8 + h]; }
    float sc = dense_b[0];
#pragma unroll
    for (int h = 0; h < 8; ++h) sc += p[h] * sv[h];
    float mx = sc;
#pragma unroll
    for (int sft = 32; sft; sft >>= 1) mx = fmaxf(mx, __shfl_xor(mx, sft));
    const float e = expf(sc - mx);
    float sm = e;
#pragma unroll
    for (int sft = 32; sft; sft >>= 1) sm += __shfl_xor(sm, sft);
    const float attn = e / sm;
    float co[8];
#pragma unroll
    for (int h = 0; h < 8; ++h) co[h] = attn * p[h];
    if      (wv == 0) { cc0 = co[0]; cc1 = co[1]; }
    else if (wv == 1) { cc0 = co[2]; cc1 = co[3]; }
    else if (wv == 2) { cc0 = co[4]; cc1 = co[5]; }
    else              { cc0 = co[6]; cc1 = co[7]; }
  }
  // Phase 4: y by head — wave w owns h=2w,2w+1; lane owns 4 d-cols; x from LDS
  {
    const unsigned int* xu = (const unsigned int*)xl;
    float y0[4] = {}, y1[4] = {};
#pragma unroll
    for (int ll = 0; ll < 64; ++ll) {
      const uint2 xv = *(const uint2*)(xu + ll * 132 + l * 2);
      const float c0 = __shfl(cc0, ll);
      const float c1 = __shfl(cc1, ll);
      const float x0 = ubf(xv.x & 0xffffu);
      const float x1 = ubf(xv.x >> 16);
      const float x2 = ubf(xv.y & 0xffffu);
      const float x3 = ubf(xv.y >> 16);
      y0[0] += c0 * x0; y0[1] += c0 * x1; y0[2] += c0 * x2; y0[3] += c0 * x3;
      y1[0] += c1 * x0; y1[1] += c1 * x1; y1[2] += c1 * x2; y1[3] += c1 * x3;
    }
    uint2 pk0, pk1;
    pk0.x = pack2bf(y0[0], y0[1]); pk0.y = pack2bf(y0[2], y0[3]);
    pk1.x = pack2bf(y1[0], y1[1]); pk1.y = pack2bf(y1[2], y1[3]);
    *(uint2*)(cbf + (size_t)b * 2048 + (2 * wv) * 256 + l * 4)     = pk0;
    *(uint2*)(cbf + (size_t)b * 2048 + (2 * wv + 1) * 256 + l * 4) = pk1;
  }
}

// ---- K4: out[8192,256] = cbf[8192,2048] @ P  (MFMA; B via Pt[n][k]; cgemm geometry)
__global__ __launch_bounds__(256) void pgemm(const unsigned short* __restrict__ cbf,
                                             const unsigned short* __restrict__ ptb,
                                             float* __restrict__ out) {
  __shared__ unsigned short As[64 * 264];   // 33,792 B: 64 rows x 256 bf16 K-chunk
  const int t = threadIdx.x;
  const int m0 = blockIdx.x * 64, n0 = blockIdx.y * 64;
  const int wv = t >> 6, l = t & 63;
  const int g = l >> 4, r = l & 15;
  f32x4 acc[4] = {};
  for (int kc = 0; kc < 8; ++kc) {          // K chunks of 256
    __syncthreads();                        // As reuse guard (no-op at kc=0)
#pragma unroll
    for (int it = 0; it < 8; ++it) {
      const int idx = it * 256 + t;          // 0..2047
      const int row = idx >> 5, c = idx & 31;
      const uint4 v = *(const uint4*)(cbf + (size_t)(m0 + row) * 2048 + kc * 256 + c * 8);
      *(uint4*)(As + row * 264 + c * 8) = v;
    }
    __syncthreads();
#pragma unroll
    for (int kk = 0; kk < 8; ++kk) {
      const bf16x8 a = *(const bf16x8*)(As + (16 * wv + r) * 264 + kk * 32 + g * 8);
#pragma unroll
      for (int nt = 0; nt < 4; ++nt) {
        const int n = n0 + nt * 16 + r;
        const bf16x8 bb = *(const bf16x8*)(ptb + (size_t)n * 2048 + kc * 256 + kk * 32 + g * 8);
        acc[nt] = __builtin_amdgcn_mfma_f32_16x16x32_bf16(a, bb, acc[nt], 0, 0, 0);
      }
    }
  }
#pragma unroll
  for (int nt = 0; nt < 4; ++nt) {
    const int n = n0 + nt * 16 + r;
#pragma unroll
    for (int i = 0; i < 4; ++i)
      out[(size_t)(m0 + 16 * wv + g * 4 + i) * 256 + n] = acc[nt][i];
  }
}

extern "C" void kernel_launch(void* const* d_in, const int* in_sizes, int n_in,
                              void* d_out, int out_size, void* d_ws, size_t ws_size,
                              hipStream_t stream) {
  const int*   tokens = (const int*)d_in[0];
  const float* emb    = (const float*)d_in[1];
  const float* WQ     = (const float*)d_in[2];
  const float* WK     = (const float*)d_in[3];
  const float* WV     = (const float*)d_in[4];
  const float* WO     = (const float*)d_in[5];
  const float* dw     = (const float*)d_in[6];
  const float* db     = (const float*)d_in[7];
  float* out = (float*)d_out;

  // ushort-unit layout
  unsigned short* base = (unsigned short*)d_ws;
  unsigned short* mbf  = base;                           // 2048
  unsigned short* xbf  = base + 2048;                    // 8192*256   (4 MB)
  unsigned short* tkn  = xbf + (size_t)8192 * 256;       // 2048*256   (1 MB)
  unsigned short* cbf  = tkn + (size_t)2048 * 256;       // 8192*2048  (32 MB)
  unsigned short* ebf  = cbf + (size_t)8192 * 2048;      // 50000*256  (25.6 MB)
  unsigned short* ptb  = ebf + (size_t)50000 * 256;      // 256*2048   (1 MB)

  const size_t need_bytes = (size_t)(2048 + 8192*256 + 2048*256 + 8192*2048
                                     + 50000*256 + 256*2048) * 2;
  if (ws_size < need_bytes) return;  // deterministic no-op guard

  prep_kernel<<<dim3(1), dim3(256), 0, stream>>>(WV, WO, dw, mbf);
  prep_T<<<dim3(256), dim3(256), 0, stream>>>(WQ, WK, tkn);
  prep_P<<<dim3(8, 8), dim3(256), 0, stream>>>(WV, WO, ptb);
  // emb f32 -> ebf bf16 (50000*256)
  ebf_kernel<<<dim3(2048), dim3(256), 0, stream>>>((const float4*)emb, (uint2*)ebf,
                                                   50000 * 64);
  xbar_kernel<<<dim3(8192), dim3(256), 0, stream>>>(tokens, ebf, xbf);
  // c[b][n] for all b,n in one MFMA GEMM
  cgemm<<<dim3(128, 32), dim3(256), 0, stream>>>(xbf, tkn, cbf);
  // main per-sample: logits, softmaxes, y (overwrites c, bf16)
  main_kernel<<<dim3(8192), dim3(256), 0, stream>>>(tokens, ebf, mbf, db, cbf);
  // out = Y @ P in one MFMA GEMM (cgemm-shaped: 512 blocks, 64x64 tile)
  pgemm<<<dim3(128, 4), dim3(256), 0, stream>>>(cbf, ptb, out);
}

// Round 13
// 274.607 us; speedup vs baseline: 1.3023x; 1.0889x over previous
//
#include <hip/hip_runtime.h>
#include <cstdint>

// NewsEncoder: B=8192, L=64, D=256, H=8, DH=32, VOCAB=50000.
// R13: main_kernel v4 — phase 4 (y = coefT @ X) moved to MFMA. 8 MFMAs/wave
// replace 512 scalar FMAs (phase 4 was ~60% of block VALU; main was
// VALU-bound at VALUBusy 42%, MfmaUtil 1.5%). coefT[16][80] bf16 in LDS
// (rows 8-15 zeroed); B-frags = 8x ds_read_u16 columns of xl. 4 barriers.
// LDS 40,704 B (still 4 blocks/CU). Everything else unchanged from R12.
// Workspace: mbf | xbf | tkn | cbf | ebf | ptb  => ~62.4 MB

using f32x4  = __attribute__((ext_vector_type(4))) float;
using bf16x8 = __attribute__((ext_vector_type(8))) short;

__device__ __forceinline__ unsigned int pack2bf(float a, float b) {
  unsigned int ua = __builtin_bit_cast(unsigned int, a);
  unsigned int ub = __builtin_bit_cast(unsigned int, b);
  ua = (ua + 0x7fffu + ((ua >> 16) & 1u)) >> 16;   // RTNE to bf16
  ub = (ub + 0x7fffu + ((ub >> 16) & 1u)) >> 16;
  return ua | (ub << 16);
}
__device__ __forceinline__ unsigned short bf1(float a) {
  unsigned int ua = __builtin_bit_cast(unsigned int, a);
  ua = (ua + 0x7fffu + ((ua >> 16) & 1u)) >> 16;
  return (unsigned short)ua;
}
__device__ __forceinline__ float ubf(unsigned int u) {
  return __builtin_bit_cast(float, u << 16);
}

// ---- prep: WOd[d] = WO[d,:]@dw;  m[h][d] = sum_j WV[d][h*32+j]*WOd[h*32+j] (bf16 out)
__global__ __launch_bounds__(256) void prep_kernel(const float* __restrict__ WV,
                                                   const float* __restrict__ WO,
                                                   const float* __restrict__ dw,
                                                   unsigned short* __restrict__ mbf) {
  __shared__ float wod[256];
  const int t = threadIdx.x;
  float acc = 0.f;
  for (int e = 0; e < 256; e += 4) {
    const float4 w4 = *(const float4*)(WO + (size_t)t * 256 + e);
    const float4 d4 = *(const float4*)(dw + e);
    acc += w4.x * d4.x + w4.y * d4.y + w4.z * d4.z + w4.w * d4.w;
  }
  wod[t] = acc;
  __syncthreads();
  for (int h = 0; h < 8; ++h) {
    float a = 0.f;
    for (int j = 0; j < 32; j += 4) {
      const float4 w4 = *(const float4*)(WV + (size_t)t * 256 + h * 32 + j);
      a += w4.x * wod[h*32+j] + w4.y * wod[h*32+j+1] + w4.z * wod[h*32+j+2] + w4.w * wod[h*32+j+3];
    }
    const float o = __shfl_xor(a, 1);
    if (!(t & 1)) ((unsigned int*)mbf)[h * 128 + (t >> 1)] = pack2bf(a, o);
  }
}

// ---- prep_T: Tkn[n=h*256+e][d] = sum_j WQ[d][hj]*WK[e][hj] + WK[d][hj]*WQ[e][hj] (bf16)
__global__ __launch_bounds__(256) void prep_T(const float* __restrict__ WQ,
                                              const float* __restrict__ WK,
                                              unsigned short* __restrict__ tkn) {
  __shared__ float ek[8][32], eq[8][32];
  const int t = threadIdx.x;
  const int n0 = blockIdx.x * 8;          // 8 n-rows per block, same head
  const int h  = n0 >> 8;
  {
    const int ei = t >> 5, j = t & 31;
    const int e = (n0 & 255) + ei;
    ek[ei][j] = WK[(size_t)e * 256 + h * 32 + j];
    eq[ei][j] = WQ[(size_t)e * 256 + h * 32 + j];
  }
  __syncthreads();
  float wqd[32], wkd[32];
#pragma unroll
  for (int j = 0; j < 32; j += 4) {
    *(float4*)(wqd + j) = *(const float4*)(WQ + (size_t)t * 256 + h * 32 + j);
    *(float4*)(wkd + j) = *(const float4*)(WK + (size_t)t * 256 + h * 32 + j);
  }
#pragma unroll
  for (int ei = 0; ei < 8; ++ei) {
    float a = 0.f;
#pragma unroll
    for (int j = 0; j < 32; ++j) a += wqd[j] * ek[ei][j] + wkd[j] * eq[ei][j];
    const float o = __shfl_xor(a, 1);
    if (!(t & 1)) ((unsigned int*)tkn)[(size_t)(n0 + ei) * 128 + (t >> 1)] = pack2bf(a, o);
  }
}

// ---- prep_P: Pt[n][h*256+d] = sum_j WV[d][h*32+j] * WO[h*32+j][n]  (bf16, transposed)
__global__ __launch_bounds__(256) void prep_P(const float* __restrict__ WV,
                                              const float* __restrict__ WO,
                                              unsigned short* __restrict__ ptb) {
  __shared__ float wvs[32][32];    // WV[d0+dd][h32+j]
  __shared__ float wos[32][256];   // WO[h32+j][n]
  const int t = threadIdx.x;
  const int h = blockIdx.x, d0 = blockIdx.y * 32;
  {
    const int dd = t >> 3, jq = (t & 7) * 4;
    *(float4*)(&wvs[dd][jq]) = *(const float4*)(WV + (size_t)(d0 + dd) * 256 + h * 32 + jq);
    const int c4 = (t & 63) * 4;
#pragma unroll
    for (int jj = 0; jj < 8; ++jj) {
      const int j = (t >> 6) * 8 + jj;
      *(float4*)(&wos[j][c4]) = *(const float4*)(WO + (size_t)(h * 32 + j) * 256 + c4);
    }
  }
  __syncthreads();
  const int n = t;
#pragma unroll 4
  for (int dd = 0; dd < 32; ++dd) {
    float a = 0.f;
#pragma unroll
    for (int j = 0; j < 32; ++j) a += wvs[dd][j] * wos[j][n];
    ptb[(size_t)n * 2048 + h * 256 + d0 + dd] = bf1(a);
  }
}

// ---- K0: convert emb (f32) -> ebf (bf16)
__global__ __launch_bounds__(256) void ebf_kernel(const float4* __restrict__ emb4,
                                                  uint2* __restrict__ out2, int n) {
  for (int i = blockIdx.x * 256 + threadIdx.x; i < n; i += gridDim.x * 256) {
    const float4 v = emb4[i];
    uint2 pk;
    pk.x = pack2bf(v.x, v.y);
    pk.y = pack2bf(v.z, v.w);
    out2[i] = pk;
  }
}

// ---- K1: xbar[b][d] = mean_l ebf[tok[b][l]][d]  (bf16 in/out, f32 accum)
__global__ __launch_bounds__(256) void xbar_kernel(const int* __restrict__ tokens,
                                                   const unsigned short* __restrict__ ebf,
                                                   unsigned short* __restrict__ xbf) {
  __shared__ int tok[64];
  __shared__ float part[4][64][4];          // 4 KB
  const int b = blockIdx.x, t = threadIdx.x;
  if (t < 64) tok[t] = tokens[b * 64 + t];
  __syncthreads();
  const int cp = t & 63, rg = t >> 6;       // col-quad, row-group
  const uint2* e2 = (const uint2*)ebf;
  float s0 = 0.f, s1 = 0.f, s2 = 0.f, s3 = 0.f;
#pragma unroll
  for (int ri = 0; ri < 16; ++ri) {
    const uint2 u = e2[(size_t)tok[rg * 16 + ri] * 64 + cp];
    s0 += ubf(u.x & 0xffffu); s1 += ubf(u.x >> 16);
    s2 += ubf(u.y & 0xffffu); s3 += ubf(u.y >> 16);
  }
  *(float4*)part[rg][cp] = make_float4(s0, s1, s2, s3);
  __syncthreads();
  if (t < 64) {
    const float4 p0 = *(const float4*)part[0][t];
    const float4 p1 = *(const float4*)part[1][t];
    const float4 p2 = *(const float4*)part[2][t];
    const float4 p3 = *(const float4*)part[3][t];
    const float a0 = (p0.x + p1.x + p2.x + p3.x) * (1.f / 64.f);
    const float a1 = (p0.y + p1.y + p2.y + p3.y) * (1.f / 64.f);
    const float a2 = (p0.z + p1.z + p2.z + p3.z) * (1.f / 64.f);
    const float a3 = (p0.w + p1.w + p2.w + p3.w) * (1.f / 64.f);
    uint2 pk;
    pk.x = pack2bf(a0, a1);
    pk.y = pack2bf(a2, a3);
    *(uint2*)((unsigned int*)xbf + (size_t)b * 128 + 2 * t) = pk;
  }
}

// ---- K2: cbf[b][n] = sum_d xbf[b][d] * tkn[n][d]  (bf16 MFMA GEMM)
__global__ __launch_bounds__(256) void cgemm(const unsigned short* __restrict__ xbf,
                                             const unsigned short* __restrict__ tkn,
                                             unsigned short* __restrict__ cbf) {
  __shared__ unsigned short As[64 * 264];   // 33,792 B
  const int t = threadIdx.x;
  const int m0 = blockIdx.x * 64, n0 = blockIdx.y * 64;
#pragma unroll
  for (int it = 0; it < 8; ++it) {
    const int idx = it * 256 + t;
    const int row = idx >> 5, c = idx & 31;
    const uint4 v = *(const uint4*)(xbf + (size_t)(m0 + row) * 256 + c * 8);
    *(uint4*)(As + row * 264 + c * 8) = v;
  }
  __syncthreads();
  const int wv = t >> 6, l = t & 63;
  const int g = l >> 4, r = l & 15;
#pragma unroll
  for (int nt = 0; nt < 4; ++nt) {
    const int n = n0 + nt * 16 + r;
    f32x4 acc = {0.f, 0.f, 0.f, 0.f};
#pragma unroll
    for (int kk = 0; kk < 8; ++kk) {
      const bf16x8 a  = *(const bf16x8*)(As + (16 * wv + r) * 264 + kk * 32 + g * 8);
      const bf16x8 bb = *(const bf16x8*)(tkn + (size_t)n * 256 + kk * 32 + g * 8);
      acc = __builtin_amdgcn_mfma_f32_16x16x32_bf16(a, bb, acc, 0, 0, 0);
    }
#pragma unroll
    for (int i = 0; i < 4; ++i)
      cbf[(size_t)(m0 + 16 * wv + g * 4 + i) * 2048 + n] = bf1(acc[i]);
  }
}

// ---- K3: main v4 — x staged once in LDS; phases 1-3 as v3; phase 4 via MFMA:
//          Y[16,256] = coefT[16,64] @ X[64,256], rows 8-15 discarded.
__global__ __launch_bounds__(256) void main_kernel(const int* __restrict__ tokens,
                                                   const unsigned short* __restrict__ ebf,
                                                   const unsigned short* __restrict__ mbf,
                                                   const float* __restrict__ dense_b,
                                                   unsigned short* __restrict__ cbf) {
  __shared__ unsigned short xl[64 * 264];   // 33,792 B: x bf16, row stride 264
  __shared__ float wslds[64 * 17];          // 4,352 B: cols 0-7 w->p, 8-15 s
  __shared__ unsigned short cfT[16 * 80];   // 2,560 B: coef^T bf16 [h][l]
  const int t = threadIdx.x;
  const int b = blockIdx.x;
  const int wv = t >> 6, l = t & 63;
  const int g = l >> 4, r = l & 15;
  // zero cfT rows 8..15 (M-padding read by MFMA; keep deterministic)
  {
    unsigned int* cz = (unsigned int*)(cfT + 8 * 80);
    for (int z = t; z < 320; z += 256) cz[z] = 0u;
  }
  // Stage x: tokens read per-thread (32-thread broadcast), 8 indep uint4 loads
  {
    const uint4* eb4 = (const uint4*)ebf;   // 16 B = 8 bf16; 32 uint4 per row
#pragma unroll
    for (int it = 0; it < 8; ++it) {
      const int idx = it * 256 + t;          // 0..2047
      const int row = idx >> 5, c = idx & 31;
      const int tk = tokens[b * 64 + row];
      *(uint4*)(xl + row * 264 + c * 8) = eb4[(size_t)tk * 32 + c];
    }
  }
  __syncthreads();                          // barrier 1: x staged
  // Phase 1: [W|S] = X[64,256] @ [c|m]^T; A from LDS, B from global (L2-hot)
  {
    const unsigned short* arow = xl + (16 * wv + r) * 264;
    const unsigned short* brow = (r < 8) ? (cbf + (size_t)b * 2048 + r * 256)
                                         : (mbf + (size_t)(r - 8) * 256);
    f32x4 acc = {0.f, 0.f, 0.f, 0.f};
#pragma unroll
    for (int kk = 0; kk < 8; ++kk) {
      const bf16x8 a  = *(const bf16x8*)(arow + kk * 32 + g * 8);
      const bf16x8 bb = *(const bf16x8*)(brow + kk * 32 + g * 8);
      acc = __builtin_amdgcn_mfma_f32_16x16x32_bf16(a, bb, acc, 0, 0, 0);
    }
#pragma unroll
    for (int i = 0; i < 4; ++i)
      wslds[(16 * wv + g * 4 + i) * 17 + r] = acc[i];
  }
  __syncthreads();                          // barrier 2: logits complete
  // Phase 2: per-head softmax over seq (wave w handles heads 2w, 2w+1)
  {
#pragma unroll
    for (int hh = 0; hh < 2; ++hh) {
      const int h = 2 * wv + hh;
      const float v = wslds[l * 17 + h];
      float mx = v;
#pragma unroll
      for (int sft = 32; sft; sft >>= 1) mx = fmaxf(mx, __shfl_xor(mx, sft));
      const float e = expf(v - mx);
      float sm = e;
#pragma unroll
      for (int sft = 32; sft; sft >>= 1) sm += __shfl_xor(sm, sft);
      wslds[l * 17 + h] = e / sm;
    }
  }
  __syncthreads();                          // barrier 3: p complete
  // Phase 3 (every wave, redundant): scores softmax -> coef -> cfT (bf16)
  {
    float p[8], sv[8];
#pragma unroll
    for (int h = 0; h < 8; ++h) { p[h] = wslds[l*17 + h]; sv[h] = wslds[l*17 + 8 + h]; }
    float sc = dense_b[0];
#pragma unroll
    for (int h = 0; h < 8; ++h) sc += p[h] * sv[h];
    float mx = sc;
#pragma unroll
    for (int sft = 32; sft; sft >>= 1) mx = fmaxf(mx, __shfl_xor(mx, sft));
    const float e = expf(sc - mx);
    float sm = e;
#pragma unroll
    for (int sft = 32; sft; sft >>= 1) sm += __shfl_xor(sm, sft);
    const float attn = e / sm;
    float cc0, cc1;
    if      (wv == 0) { cc0 = attn * p[0]; cc1 = attn * p[1]; }
    else if (wv == 1) { cc0 = attn * p[2]; cc1 = attn * p[3]; }
    else if (wv == 2) { cc0 = attn * p[4]; cc1 = attn * p[5]; }
    else              { cc0 = attn * p[6]; cc1 = attn * p[7]; }
    cfT[(2 * wv) * 80 + l]     = bf1(cc0);   // coefT[h][l]
    cfT[(2 * wv + 1) * 80 + l] = bf1(cc1);
  }
  __syncthreads();                          // barrier 4: cfT ready
  // Phase 4: Y = coefT @ X via MFMA. Wave wv covers d in [wv*64, wv*64+64).
  {
    const bf16x8 a0 = *(const bf16x8*)(cfT + r * 80 + g * 8);        // k = 0..31
    const bf16x8 a1 = *(const bf16x8*)(cfT + r * 80 + 32 + g * 8);   // k = 32..63
    const short* xs = (const short*)xl;
#pragma unroll
    for (int nt = 0; nt < 4; ++nt) {
      const int d = wv * 64 + nt * 16 + r;
      short bv0[8], bv1[8];
#pragma unroll
      for (int j = 0; j < 8; ++j) {
        bv0[j] = xs[(g * 8 + j) * 264 + d];        // X[l=g*8+j][d]
        bv1[j] = xs[(32 + g * 8 + j) * 264 + d];   // X[l=32+g*8+j][d]
      }
      f32x4 acc = {0.f, 0.f, 0.f, 0.f};
      acc = __builtin_amdgcn_mfma_f32_16x16x32_bf16(a0, *(const bf16x8*)bv0, acc, 0, 0, 0);
      acc = __builtin_amdgcn_mfma_f32_16x16x32_bf16(a1, *(const bf16x8*)bv1, acc, 0, 0, 0);
      if (g < 2) {
#pragma unroll
        for (int i = 0; i < 4; ++i) {
          const int h = g * 4 + i;                  // rows 0..7 valid
          cbf[(size_t)b * 2048 + h * 256 + d] = bf1(acc[i]);
        }
      }
    }
  }
}

// ---- K4: out[8192,256] = cbf[8192,2048] @ P  (MFMA; B via Pt[n][k]; cgemm geometry)
__global__ __launch_bounds__(256) void pgemm(const unsigned short* __restrict__ cbf,
                                             const unsigned short* __restrict__ ptb,
                                             float* __restrict__ out) {
  __shared__ unsigned short As[64 * 264];   // 33,792 B: 64 rows x 256 bf16 K-chunk
  const int t = threadIdx.x;
  const int m0 = blockIdx.x * 64, n0 = blockIdx.y * 64;
  const int wv = t >> 6, l = t & 63;
  const int g = l >> 4, r = l & 15;
  f32x4 acc[4] = {};
  for (int kc = 0; kc < 8; ++kc) {          // K chunks of 256
    __syncthreads();                        // As reuse guard (no-op at kc=0)
#pragma unroll
    for (int it = 0; it < 8; ++it) {
      const int idx = it * 256 + t;          // 0..2047
      const int row = idx >> 5, c = idx & 31;
      const uint4 v = *(const uint4*)(cbf + (size_t)(m0 + row) * 2048 + kc * 256 + c * 8);
      *(uint4*)(As + row * 264 + c * 8) = v;
    }
    __syncthreads();
#pragma unroll
    for (int kk = 0; kk < 8; ++kk) {
      const bf16x8 a = *(const bf16x8*)(As + (16 * wv + r) * 264 + kk * 32 + g * 8);
#pragma unroll
      for (int nt = 0; nt < 4; ++nt) {
        const int n = n0 + nt * 16 + r;
        const bf16x8 bb = *(const bf16x8*)(ptb + (size_t)n * 2048 + kc * 256 + kk * 32 + g * 8);
        acc[nt] = __builtin_amdgcn_mfma_f32_16x16x32_bf16(a, bb, acc[nt], 0, 0, 0);
      }
    }
  }
#pragma unroll
  for (int nt = 0; nt < 4; ++nt) {
    const int n = n0 + nt * 16 + r;
#pragma unroll
    for (int i = 0; i < 4; ++i)
      out[(size_t)(m0 + 16 * wv + g * 4 + i) * 256 + n] = acc[nt][i];
  }
}

extern "C" void kernel_launch(void* const* d_in, const int* in_sizes, int n_in,
                              void* d_out, int out_size, void* d_ws, size_t ws_size,
                              hipStream_t stream) {
  const int*   tokens = (const int*)d_in[0];
  const float* emb    = (const float*)d_in[1];
  const float* WQ     = (const float*)d_in[2];
  const float* WK     = (const float*)d_in[3];
  const float* WV     = (const float*)d_in[4];
  const float* WO     = (const float*)d_in[5];
  const float* dw     = (const float*)d_in[6];
  const float* db     = (const float*)d_in[7];
  float* out = (float*)d_out;

  // ushort-unit layout
  unsigned short* base = (unsigned short*)d_ws;
  unsigned short* mbf  = base;                           // 2048
  unsigned short* xbf  = base + 2048;                    // 8192*256   (4 MB)
  unsigned short* tkn  = xbf + (size_t)8192 * 256;       // 2048*256   (1 MB)
  unsigned short* cbf  = tkn + (size_t)2048 * 256;       // 8192*2048  (32 MB)
  unsigned short* ebf  = cbf + (size_t)8192 * 2048;      // 50000*256  (25.6 MB)
  unsigned short* ptb  = ebf + (size_t)50000 * 256;      // 256*2048   (1 MB)

  const size_t need_bytes = (size_t)(2048 + 8192*256 + 2048*256 + 8192*2048
                                     + 50000*256 + 256*2048) * 2;
  if (ws_size < need_bytes) return;  // deterministic no-op guard

  prep_kernel<<<dim3(1), dim3(256), 0, stream>>>(WV, WO, dw, mbf);
  prep_T<<<dim3(256), dim3(256), 0, stream>>>(WQ, WK, tkn);
  prep_P<<<dim3(8, 8), dim3(256), 0, stream>>>(WV, WO, ptb);
  // emb f32 -> ebf bf16 (50000*256)
  ebf_kernel<<<dim3(2048), dim3(256), 0, stream>>>((const float4*)emb, (uint2*)ebf,
                                                   50000 * 64);
  xbar_kernel<<<dim3(8192), dim3(256), 0, stream>>>(tokens, ebf, xbf);
  // c[b][n] for all b,n in one MFMA GEMM
  cgemm<<<dim3(128, 32), dim3(256), 0, stream>>>(xbf, tkn, cbf);
  // main per-sample: logits, softmaxes, y via MFMA (overwrites c, bf16)
  main_kernel<<<dim3(8192), dim3(256), 0, stream>>>(tokens, ebf, mbf, db, cbf);
  // out = Y @ P in one MFMA GEMM (cgemm-shaped: 512 blocks, 64x64 tile)
  pgemm<<<dim3(128, 4), dim3(256), 0, stream>>>(cbf, ptb, out);
}